// Round 1
// baseline (1562.709 us; speedup 1.0000x reference)
//
#include <hip/hip_runtime.h>
#include <cstdint>
#include <cstddef>

#define BB 32
#define TT 300
#define DD 2312
#define HH 800
#define OO 10
#define CAP1 128

// exp(-1/20), exp(-1/5) correctly rounded to fp32
#define DM_F 0.95122942450071400909f
#define DS_F 0.81873075307798185867f

// d_out float offsets (concatenated tuple, return order)
#define OUT_T_OFF 0
#define OUT_U_OFF 320
#define SUM_OFF   640
#define H1V_OFF   643ull
#define H2V_OFF   59187843ull
#define H1DV_OFF  59443843ull
#define H2DV_OFF  118631043ull
#define H1DT_OFF  118887043ull
#define H2DT_OFF  118912643ull

// ws byte offsets (all 256-aligned)
#define WS_W1T  0ull
#define WS_C1   7398400ull
#define WS_IDX1 38118400ull          // u16[BB*TT*CAP1]
#define WS_IDX2 40576000ull          // u16[BB*TT*HH]
#define WS_CNT1 55936000ull          // int[BB*TT]
#define WS_CNT2 55974400ull          // int[BB*TT]
#define WS_T1   56012800ull          // int[BB*HH]
#define WS_T2   56115200ull          // int[BB*OO]
#define WS_DMP  56116480ull          // float[TT+1]
#define WS_DSP  56117760ull          // float[TT+1]

__global__ void k_pow(float* __restrict__ dmp, float* __restrict__ dsp) {
    if (threadIdx.x == 0) {
        float v = 1.f;
        for (int i = 0; i <= TT; ++i) { dmp[i] = v; v *= DM_F; }
    }
    if (threadIdx.x == 1) {
        float v = 1.f;
        for (int i = 0; i <= TT; ++i) { dsp[i] = v; v *= DS_F; }
    }
}

__global__ void k_transpose(const float* __restrict__ W1, float* __restrict__ W1T) {
    __shared__ float tile[32][33];
    int dx = blockIdx.x * 32, hy = blockIdx.y * 32;
    int tx = threadIdx.x, ty = threadIdx.y;
    int d = dx + tx, h = hy + ty;            // h always < 800 (25*32)
    if (d < DD) tile[ty][tx] = W1[(size_t)h * DD + d];
    __syncthreads();
    int d2 = dx + ty, h2 = hy + tx;
    if (d2 < DD) W1T[(size_t)d2 * HH + h2] = tile[tx][ty];
}

// Build per-(b,t) lists of active input indices; count total input spikes.
__global__ void k_events(const float* __restrict__ in, int* __restrict__ cnt1,
                         unsigned short* __restrict__ idx1, float* __restrict__ out) {
    int row = blockIdx.x * 4 + (threadIdx.x >> 6);   // (b,din) row, rows = BB*DD
    int lane = threadIdx.x & 63;
    if (row >= BB * DD) return;
    int b = row / DD, din = row - b * DD;
    const float* p = in + (size_t)row * TT;
    int total = 0;
    for (int r = 0; r < 5; ++r) {
        int t = r * 64 + lane;
        float v = (t < TT) ? p[t] : 0.f;
        bool act = (v != 0.f);
        if (act) {
            int pos = atomicAdd(&cnt1[b * TT + t], 1);
            if (pos < CAP1) idx1[(size_t)(b * TT + t) * CAP1 + pos] = (unsigned short)din;
        }
        unsigned long long m = __ballot(act);
        if (lane == 0) total += __popcll(m);
    }
    if (lane == 0 && total) atomicAdd(&out[SUM_OFF + 0], (float)total);
}

// c1[b,t,:] = sum over active din of W1T[din,:]
__global__ __launch_bounds__(256) void k_c1(const int* __restrict__ cnt1,
                                            const unsigned short* __restrict__ idx1,
                                            const float* __restrict__ W1T,
                                            float* __restrict__ c1) {
    int blk = blockIdx.x;                 // b*TT + t
    int cnt = cnt1[blk];
    if (cnt > CAP1) cnt = CAP1;
    __shared__ int sidx[CAP1];
    for (int j = threadIdx.x; j < cnt; j += 256) sidx[j] = idx1[(size_t)blk * CAP1 + j];
    __syncthreads();
    int tid = threadIdx.x;
    if (tid < 200) {
        float ax = 0.f, ay = 0.f, az = 0.f, aw = 0.f;
        for (int j = 0; j < cnt; ++j) {
            const float4* row = (const float4*)(W1T + (size_t)sidx[j] * HH);
            float4 w = row[tid];
            ax += w.x; ay += w.y; az += w.z; aw += w.w;
        }
        float4 o; o.x = ax; o.y = ay; o.z = az; o.w = aw;
        ((float4*)(c1 + (size_t)blk * HH))[tid] = o;
    }
}

// Per-(b,h): scan um/us recurrence, find first crossing -> t1, h1_dtdu, spk1 lists.
__global__ void k_scan1(const float* __restrict__ c1, int* __restrict__ t1,
                        int* __restrict__ cnt2, unsigned short* __restrict__ idx2,
                        float* __restrict__ out) {
    int id = blockIdx.x * 256 + threadIdx.x;   // 25600 = 100 * 256
    int b = id / HH, h = id - b * HH;
    float um = 0.f, us = 0.f;
    bool done = false;
    int t1v = TT;
    const float* cbase = c1 + (size_t)b * TT * HH + h;
    for (int t = 0; t < TT; ++t) {
        float c = cbase[(size_t)t * HH];
        um = um * DM_F + c;
        us = us * DS_F + c;
        float u = um - us;
        if (u >= 1.0f) {
            done = true; t1v = t;
            float dudt = -um / 20.0f + us / 5.0f;
            dudt = (dudt >= 0.f) ? fmaxf(dudt, 1e-2f) : fminf(dudt, -1e-2f);
            out[H1DT_OFF + (size_t)id] = 1.f / dudt;
            int pos = atomicAdd(&cnt2[b * TT + t], 1);
            idx2[(size_t)(b * TT + t) * HH + pos] = (unsigned short)h;
            break;
        }
    }
    if (!done) out[H1DT_OFF + (size_t)id] = 0.f;
    t1[id] = t1v;
    unsigned long long m = __ballot(done);
    if ((threadIdx.x & 63) == 0 && m) atomicAdd(&out[SUM_OFF + 1], (float)__popcll(m));
}

// Layer-2 scan per batch: out_t, out_u, h2_dtdu, t2, spk2 count.
__global__ void k_layer2(const int* __restrict__ cnt2, const unsigned short* __restrict__ idx2,
                         const float* __restrict__ W2, int* __restrict__ t2,
                         float* __restrict__ out) {
    int b = blockIdx.x, tid = threadIdx.x;   // 64 threads, lanes 0..9 own outputs
    float um = 0.f, us = 0.f, u2 = 0.f, dtdu = 0.f;
    bool done = false;
    int t2v = TT;
    for (int t = 0; t < TT; ++t) {
        float c = 0.f;
        int cnt = cnt2[b * TT + t];
        if (tid < OO) {
            const unsigned short* lp = idx2 + (size_t)(b * TT + t) * HH;
            for (int j = 0; j < cnt; ++j) {
                int hh = lp[j];
                c += W2[tid * HH + hh];
            }
        }
        um = um * DM_F + c;
        us = us * DS_F + c;
        if (!done) {
            float u = um - us;
            if (u >= 1.0f) {
                done = true; t2v = t; u2 = u;
                float dudt = -um / 20.0f + us / 5.0f;
                dudt = (dudt >= 0.f) ? fmaxf(dudt, 1e-2f) : fminf(dudt, -1e-2f);
                dtdu = 1.f / dudt;
            }
        }
    }
    if (tid < OO) {
        out[OUT_T_OFF + b * OO + tid] = (float)t2v;
        out[OUT_U_OFF + b * OO + tid] = done ? u2 : 0.f;
        out[H2DT_OFF + (size_t)(b * OO + tid)] = done ? dtdu : 0.f;
        t2[b * OO + tid] = t2v;
    }
    unsigned long long m = __ballot(done && tid < OO);
    if (tid == 0 && m) atomicAdd(&out[SUM_OFF + 2], (float)__popcll(m));
}

// Closed-form h2_v / h2_dvdt: vm2(t2) = dm^(t2-t1) for single hidden spike.
__global__ void k_h2(const int* __restrict__ t1, const int* __restrict__ t2,
                     const float* __restrict__ dmp, const float* __restrict__ dsp,
                     float* __restrict__ out) {
    int blk = blockIdx.x;         // b*OO + o
    int b = blk / OO;
    int t2v = t2[blk];
    bool spk = (t2v < TT);
    for (int h = threadIdx.x; h < HH; h += 256) {
        float v = 0.f, dv = 0.f;
        if (spk) {
            int t1v = t1[b * HH + h];
            if (t1v <= t2v) {
                int k = t2v - t1v;
                float a = dmp[k], s = dsp[k];
                v = a - s;
                dv = a / 20.0f - s / 5.0f;
            }
        }
        out[H2V_OFF + (size_t)blk * HH + h] = v;
        out[H2DV_OFF + (size_t)blk * HH + h] = dv;
    }
}

// Recompute vm1/vs1 trajectories per (b, din-chunk); write h1_v / h1_dvdt rows
// at hidden-spike times, zeros for non-spiking h.
__global__ __launch_bounds__(320) void k_h1(const float* __restrict__ in,
                                            const int* __restrict__ cnt2,
                                            const unsigned short* __restrict__ idx2,
                                            const int* __restrict__ t1,
                                            float* __restrict__ out) {
    int b = blockIdx.x >> 3, chunk = blockIdx.x & 7;
    if (threadIdx.x >= 289) return;            // 8 * 289 = 2312
    int d = chunk * 289 + threadIdx.x;
    const float* p = in + ((size_t)b * DD + d) * TT;
    float vm = 0.f, vs = 0.f;
    for (int t = 0; t < TT; ++t) {
        float x = p[t];
        vm = vm * DM_F + x;
        vs = vs * DS_F + x;
        int cnt = cnt2[b * TT + t];
        if (cnt) {
            const unsigned short* lp = idx2 + (size_t)(b * TT + t) * HH;
            float v = vm - vs;
            float dv = vm / 20.0f - vs / 5.0f;
            for (int j = 0; j < cnt; ++j) {
                int h = lp[j];
                size_t ro = (size_t)(b * HH + h) * DD + d;
                out[H1V_OFF + ro] = v;
                out[H1DV_OFF + ro] = dv;
            }
        }
    }
    for (int h = 0; h < HH; ++h) {
        if (t1[b * HH + h] >= TT) {
            size_t ro = (size_t)(b * HH + h) * DD + d;
            out[H1V_OFF + ro] = 0.f;
            out[H1DV_OFF + ro] = 0.f;
        }
    }
}

extern "C" void kernel_launch(void* const* d_in, const int* in_sizes, int n_in,
                              void* d_out, int out_size, void* d_ws, size_t ws_size,
                              hipStream_t stream) {
    (void)in_sizes; (void)n_in; (void)out_size; (void)ws_size;
    const float* in = (const float*)d_in[0];
    const float* W1 = (const float*)d_in[1];
    const float* W2 = (const float*)d_in[2];
    float* out = (float*)d_out;
    char* ws = (char*)d_ws;

    float* W1T = (float*)(ws + WS_W1T);
    float* c1  = (float*)(ws + WS_C1);
    unsigned short* idx1 = (unsigned short*)(ws + WS_IDX1);
    unsigned short* idx2 = (unsigned short*)(ws + WS_IDX2);
    int* cnt1 = (int*)(ws + WS_CNT1);
    int* cnt2 = (int*)(ws + WS_CNT2);
    int* t1   = (int*)(ws + WS_T1);
    int* t2   = (int*)(ws + WS_T2);
    float* dmp = (float*)(ws + WS_DMP);
    float* dsp = (float*)(ws + WS_DSP);

    // zero counters (cnt1 & cnt2 adjacent) and sum_sp outputs
    hipMemsetAsync(cnt1, 0, (size_t)BB * TT * 4 * 2, stream);
    hipMemsetAsync(out + SUM_OFF, 0, 3 * sizeof(float), stream);

    k_pow<<<1, 64, 0, stream>>>(dmp, dsp);
    k_transpose<<<dim3(73, 25), dim3(32, 32), 0, stream>>>(W1, W1T);
    k_events<<<(BB * DD + 3) / 4, 256, 0, stream>>>(in, cnt1, idx1, out);
    k_c1<<<BB * TT, 256, 0, stream>>>(cnt1, idx1, W1T, c1);
    k_scan1<<<(BB * HH) / 256, 256, 0, stream>>>(c1, t1, cnt2, idx2, out);
    k_layer2<<<BB, 64, 0, stream>>>(cnt2, idx2, W2, t2, out);
    k_h2<<<BB * OO, 256, 0, stream>>>(t1, t2, dmp, dsp, out);
    k_h1<<<BB * 8, 320, 0, stream>>>(in, cnt2, idx2, t1, out);
}

// Round 2
// 725.892 us; speedup vs baseline: 2.1528x; 2.1528x over previous
//
#include <hip/hip_runtime.h>
#include <cstdint>
#include <cstddef>

#define BB 32
#define TT 300
#define DD 2312
#define HH 800
#define OO 10
#define CAP1 128

// exp(-1/20), exp(-1/5) correctly rounded to fp32
#define DM_F 0.95122942450071400909f
#define DS_F 0.81873075307798185867f

// d_out float offsets (concatenated tuple, return order)
#define OUT_T_OFF 0
#define OUT_U_OFF 320
#define SUM_OFF   640
#define H1V_OFF   643ull
#define H2V_OFF   59187843ull
#define H1DV_OFF  59443843ull
#define H2DV_OFF  118631043ull
#define H1DT_OFF  118887043ull
#define H2DT_OFF  118912643ull

// ws byte offsets (all 256-aligned)
#define WS_W1T  0ull
#define WS_C1   7398400ull
#define WS_IDX1 38118400ull          // u16[BB*TT*CAP1]
#define WS_IDX2 40576000ull          // u16[BB*TT*HH]
#define WS_CNT1 55936000ull          // int[BB*TT]
#define WS_CNT2 55974400ull          // int[BB*TT]
#define WS_T1   56012800ull          // int[BB*HH]
#define WS_T2   56115200ull          // int[BB*OO]
#define WS_DMP  56116480ull          // float[TT+1]
#define WS_DSP  56117760ull          // float[TT+1]

__global__ void k_pow(float* __restrict__ dmp, float* __restrict__ dsp) {
    if (threadIdx.x == 0) {
        float v = 1.f;
        for (int i = 0; i <= TT; ++i) { dmp[i] = v; v *= DM_F; }
    }
    if (threadIdx.x == 1) {
        float v = 1.f;
        for (int i = 0; i <= TT; ++i) { dsp[i] = v; v *= DS_F; }
    }
}

__global__ void k_transpose(const float* __restrict__ W1, float* __restrict__ W1T) {
    __shared__ float tile[32][33];
    int dx = blockIdx.x * 32, hy = blockIdx.y * 32;
    int tx = threadIdx.x, ty = threadIdx.y;
    int d = dx + tx, h = hy + ty;            // h always < 800 (25*32)
    if (d < DD) tile[ty][tx] = W1[(size_t)h * DD + d];
    __syncthreads();
    int d2 = dx + ty, h2 = hy + tx;
    if (d2 < DD) W1T[(size_t)d2 * HH + h2] = tile[tx][ty];
}

// Build per-(b,t) lists of active input indices. NO single-address atomics:
// sum_sp[0] is reduced from cnt1 later (k_sum0).
__global__ void k_events(const float* __restrict__ in, int* __restrict__ cnt1,
                         unsigned short* __restrict__ idx1) {
    int row = blockIdx.x * 4 + (threadIdx.x >> 6);   // (b,din) row, rows = BB*DD
    int lane = threadIdx.x & 63;
    if (row >= BB * DD) return;
    int b = row / DD, din = row - b * DD;
    const float* p = in + (size_t)row * TT;
    for (int r = 0; r < 5; ++r) {
        int t = r * 64 + lane;
        float v = (t < TT) ? p[t] : 0.f;
        if (v != 0.f) {
            int pos = atomicAdd(&cnt1[b * TT + t], 1);
            if (pos < CAP1) idx1[(size_t)(b * TT + t) * CAP1 + pos] = (unsigned short)din;
        }
    }
}

// Reduce cnt1 -> sum_sp[0]
__global__ void k_sum0(const int* __restrict__ cnt1, float* __restrict__ out) {
    __shared__ int red[4];
    int s = 0;
    for (int i = threadIdx.x; i < BB * TT; i += 256) s += cnt1[i];
    for (int d = 32; d >= 1; d >>= 1) s += __shfl_down(s, d, 64);
    int w = threadIdx.x >> 6;
    if ((threadIdx.x & 63) == 0) red[w] = s;
    __syncthreads();
    if (threadIdx.x == 0)
        out[SUM_OFF + 0] = (float)(red[0] + red[1] + red[2] + red[3]);
}

// c1[b,t,:] = sum over active din of W1T[din,:]
__global__ __launch_bounds__(256) void k_c1(const int* __restrict__ cnt1,
                                            const unsigned short* __restrict__ idx1,
                                            const float* __restrict__ W1T,
                                            float* __restrict__ c1) {
    int blk = blockIdx.x;                 // b*TT + t
    int cnt = cnt1[blk];
    if (cnt > CAP1) cnt = CAP1;
    __shared__ int sidx[CAP1];
    for (int j = threadIdx.x; j < cnt; j += 256) sidx[j] = idx1[(size_t)blk * CAP1 + j];
    __syncthreads();
    int tid = threadIdx.x;
    if (tid < 200) {
        float ax = 0.f, ay = 0.f, az = 0.f, aw = 0.f;
        for (int j = 0; j < cnt; ++j) {
            const float4* row = (const float4*)(W1T + (size_t)sidx[j] * HH);
            float4 w = row[tid];
            ax += w.x; ay += w.y; az += w.z; aw += w.w;
        }
        float4 o; o.x = ax; o.y = ay; o.z = az; o.w = aw;
        ((float4*)(c1 + (size_t)blk * HH))[tid] = o;
    }
}

// Per-(b,h): scan um/us recurrence, find first crossing -> t1, h1_dtdu, spk1 lists.
__global__ void k_scan1(const float* __restrict__ c1, int* __restrict__ t1,
                        int* __restrict__ cnt2, unsigned short* __restrict__ idx2,
                        float* __restrict__ out) {
    int id = blockIdx.x * 256 + threadIdx.x;   // 25600 = 100 * 256
    int b = id / HH, h = id - b * HH;
    float um = 0.f, us = 0.f;
    bool done = false;
    int t1v = TT;
    const float* cbase = c1 + (size_t)b * TT * HH + h;
    for (int t = 0; t < TT; ++t) {
        float c = cbase[(size_t)t * HH];
        um = um * DM_F + c;
        us = us * DS_F + c;
        float u = um - us;
        if (u >= 1.0f) {
            done = true; t1v = t;
            float dudt = -um / 20.0f + us / 5.0f;
            dudt = (dudt >= 0.f) ? fmaxf(dudt, 1e-2f) : fminf(dudt, -1e-2f);
            out[H1DT_OFF + (size_t)id] = 1.f / dudt;
            int pos = atomicAdd(&cnt2[b * TT + t], 1);
            idx2[(size_t)(b * TT + t) * HH + pos] = (unsigned short)h;
            break;
        }
    }
    if (!done) out[H1DT_OFF + (size_t)id] = 0.f;
    t1[id] = t1v;
    unsigned long long m = __ballot(done);
    if ((threadIdx.x & 63) == 0 && m) atomicAdd(&out[SUM_OFF + 1], (float)__popcll(m));
}

// Layer-2 scan per batch: out_t, out_u, h2_dtdu, t2, spk2 count.
__global__ void k_layer2(const int* __restrict__ cnt2, const unsigned short* __restrict__ idx2,
                         const float* __restrict__ W2, int* __restrict__ t2,
                         float* __restrict__ out) {
    int b = blockIdx.x, tid = threadIdx.x;   // 64 threads, lanes 0..9 own outputs
    float um = 0.f, us = 0.f, u2 = 0.f, dtdu = 0.f;
    bool done = false;
    int t2v = TT;
    for (int t = 0; t < TT; ++t) {
        float c = 0.f;
        int cnt = cnt2[b * TT + t];
        if (tid < OO) {
            const unsigned short* lp = idx2 + (size_t)(b * TT + t) * HH;
            for (int j = 0; j < cnt; ++j) {
                int hh = lp[j];
                c += W2[tid * HH + hh];
            }
        }
        um = um * DM_F + c;
        us = us * DS_F + c;
        if (!done) {
            float u = um - us;
            if (u >= 1.0f) {
                done = true; t2v = t; u2 = u;
                float dudt = -um / 20.0f + us / 5.0f;
                dudt = (dudt >= 0.f) ? fmaxf(dudt, 1e-2f) : fminf(dudt, -1e-2f);
                dtdu = 1.f / dudt;
            }
        }
    }
    if (tid < OO) {
        out[OUT_T_OFF + b * OO + tid] = (float)t2v;
        out[OUT_U_OFF + b * OO + tid] = done ? u2 : 0.f;
        out[H2DT_OFF + (size_t)(b * OO + tid)] = done ? dtdu : 0.f;
        t2[b * OO + tid] = t2v;
    }
    unsigned long long m = __ballot(done && tid < OO);
    if (tid == 0 && m) atomicAdd(&out[SUM_OFF + 2], (float)__popcll(m));
}

// Closed-form h2_v / h2_dvdt: vm2(t2) = dm^(t2-t1) for single hidden spike.
__global__ void k_h2(const int* __restrict__ t1, const int* __restrict__ t2,
                     const float* __restrict__ dmp, const float* __restrict__ dsp,
                     float* __restrict__ out) {
    int blk = blockIdx.x;         // b*OO + o
    int b = blk / OO;
    int t2v = t2[blk];
    bool spk = (t2v < TT);
    for (int h = threadIdx.x; h < HH; h += 256) {
        float v = 0.f, dv = 0.f;
        if (spk) {
            int t1v = t1[b * HH + h];
            if (t1v <= t2v) {
                int k = t2v - t1v;
                float a = dmp[k], s = dsp[k];
                v = a - s;
                dv = a / 20.0f - s / 5.0f;
            }
        }
        out[H2V_OFF + (size_t)blk * HH + h] = v;
        out[H2DV_OFF + (size_t)blk * HH + h] = dv;
    }
}

// Recompute vm1/vs1 trajectories per (b, din-chunk); write h1_v / h1_dvdt rows
// at hidden-spike times, zeros for non-spiking h.
__global__ __launch_bounds__(320) void k_h1(const float* __restrict__ in,
                                            const int* __restrict__ cnt2,
                                            const unsigned short* __restrict__ idx2,
                                            const int* __restrict__ t1,
                                            float* __restrict__ out) {
    int b = blockIdx.x >> 3, chunk = blockIdx.x & 7;
    if (threadIdx.x >= 289) return;            // 8 * 289 = 2312
    int d = chunk * 289 + threadIdx.x;
    const float* p = in + ((size_t)b * DD + d) * TT;
    float vm = 0.f, vs = 0.f;
    for (int t = 0; t < TT; ++t) {
        float x = p[t];
        vm = vm * DM_F + x;
        vs = vs * DS_F + x;
        int cnt = cnt2[b * TT + t];
        if (cnt) {
            const unsigned short* lp = idx2 + (size_t)(b * TT + t) * HH;
            float v = vm - vs;
            float dv = vm / 20.0f - vs / 5.0f;
            for (int j = 0; j < cnt; ++j) {
                int h = lp[j];
                size_t ro = (size_t)(b * HH + h) * DD + d;
                out[H1V_OFF + ro] = v;
                out[H1DV_OFF + ro] = dv;
            }
        }
    }
    for (int h = 0; h < HH; ++h) {
        if (t1[b * HH + h] >= TT) {
            size_t ro = (size_t)(b * HH + h) * DD + d;
            out[H1V_OFF + ro] = 0.f;
            out[H1DV_OFF + ro] = 0.f;
        }
    }
}

extern "C" void kernel_launch(void* const* d_in, const int* in_sizes, int n_in,
                              void* d_out, int out_size, void* d_ws, size_t ws_size,
                              hipStream_t stream) {
    (void)in_sizes; (void)n_in; (void)out_size; (void)ws_size;
    const float* in = (const float*)d_in[0];
    const float* W1 = (const float*)d_in[1];
    const float* W2 = (const float*)d_in[2];
    float* out = (float*)d_out;
    char* ws = (char*)d_ws;

    float* W1T = (float*)(ws + WS_W1T);
    float* c1  = (float*)(ws + WS_C1);
    unsigned short* idx1 = (unsigned short*)(ws + WS_IDX1);
    unsigned short* idx2 = (unsigned short*)(ws + WS_IDX2);
    int* cnt1 = (int*)(ws + WS_CNT1);
    int* cnt2 = (int*)(ws + WS_CNT2);
    int* t1   = (int*)(ws + WS_T1);
    int* t2   = (int*)(ws + WS_T2);
    float* dmp = (float*)(ws + WS_DMP);
    float* dsp = (float*)(ws + WS_DSP);

    // zero counters (cnt1 & cnt2 adjacent) and sum_sp outputs
    hipMemsetAsync(cnt1, 0, (size_t)BB * TT * 4 * 2, stream);
    hipMemsetAsync(out + SUM_OFF, 0, 3 * sizeof(float), stream);

    k_pow<<<1, 64, 0, stream>>>(dmp, dsp);
    k_transpose<<<dim3(73, 25), dim3(32, 32), 0, stream>>>(W1, W1T);
    k_events<<<(BB * DD + 3) / 4, 256, 0, stream>>>(in, cnt1, idx1);
    k_sum0<<<1, 256, 0, stream>>>(cnt1, out);
    k_c1<<<BB * TT, 256, 0, stream>>>(cnt1, idx1, W1T, c1);
    k_scan1<<<(BB * HH) / 256, 256, 0, stream>>>(c1, t1, cnt2, idx2, out);
    k_layer2<<<BB, 64, 0, stream>>>(cnt2, idx2, W2, t2, out);
    k_h2<<<BB * OO, 256, 0, stream>>>(t1, t2, dmp, dsp, out);
    k_h1<<<BB * 8, 320, 0, stream>>>(in, cnt2, idx2, t1, out);
}

// Round 3
// 662.375 us; speedup vs baseline: 2.3593x; 1.0959x over previous
//
#include <hip/hip_runtime.h>
#include <cstdint>
#include <cstddef>

#define BB 32
#define TT 300
#define DD 2312
#define HH 800
#define OO 10
#define CAP1 128
#define KMAX 32

// exp(-1/20), exp(-1/5) correctly rounded to fp32
#define DM_F 0.95122942450071400909f
#define DS_F 0.81873075307798185867f

// d_out float offsets (concatenated tuple, return order)
#define OUT_T_OFF 0
#define OUT_U_OFF 320
#define SUM_OFF   640
#define H1V_OFF   643ull
#define H2V_OFF   59187843ull
#define H1DV_OFF  59443843ull
#define H2DV_OFF  118631043ull
#define H1DT_OFF  118887043ull
#define H2DT_OFF  118912643ull

// ws byte offsets (all 256-aligned)
#define WS_W1T    0ull
#define WS_C1     7398400ull
#define WS_IDX1   38118400ull        // u16[BB*TT*CAP1]
#define WS_IDX2   40576000ull        // u16[BB*TT*HH]
#define WS_CNT1   55936000ull        // int[BB*TT]
#define WS_CNT2   55974400ull        // int[BB*TT]
#define WS_T1     56012800ull        // int[BB*HH]
#define WS_T2     56115200ull        // int[BB*OO]
#define WS_DMP    56116480ull        // float[TT+1]
#define WS_DSP    56117760ull        // float[TT+1]
#define WS_TIMES1 56119040ull        // u16[BB*DD*KMAX]  (4,734,976 B)
#define WS_KCNT   60854016ull        // int[BB*DD]       (295,936 B)

__global__ void k_pow(float* __restrict__ dmp, float* __restrict__ dsp) {
    if (threadIdx.x == 0) {
        float v = 1.f;
        for (int i = 0; i <= TT; ++i) { dmp[i] = v; v *= DM_F; }
    }
    if (threadIdx.x == 1) {
        float v = 1.f;
        for (int i = 0; i <= TT; ++i) { dsp[i] = v; v *= DS_F; }
    }
}

__global__ void k_transpose(const float* __restrict__ W1, float* __restrict__ W1T) {
    __shared__ float tile[32][33];
    int dx = blockIdx.x * 32, hy = blockIdx.y * 32;
    int tx = threadIdx.x, ty = threadIdx.y;
    int d = dx + tx, h = hy + ty;            // h always < 800 (25*32)
    if (d < DD) tile[ty][tx] = W1[(size_t)h * DD + d];
    __syncthreads();
    int d2 = dx + ty, h2 = hy + tx;
    if (d2 < DD) W1T[(size_t)d2 * HH + h2] = tile[tx][ty];
}

// One wave per (b,din) row. Builds:
//  - per-(b,t) active-input lists (cnt1/idx1, via distributed atomics) for k_c1
//  - per-(b,din) ordered spike-time lists (times1/kcnt, ballot-prefix, no atomics)
__global__ void k_events(const float* __restrict__ in, int* __restrict__ cnt1,
                         unsigned short* __restrict__ idx1,
                         unsigned short* __restrict__ times1, int* __restrict__ kcnt) {
    int row = blockIdx.x * 4 + (threadIdx.x >> 6);   // rows = BB*DD = 73984 (divisible by 4)
    int lane = threadIdx.x & 63;
    int b = row / DD, din = row - b * DD;
    const float* p = in + (size_t)row * TT;
    int kbase = 0;
    for (int r = 0; r < 5; ++r) {
        int t = r * 64 + lane;
        float v = (t < TT) ? p[t] : 0.f;
        bool act = (v != 0.f);
        unsigned long long m = __ballot(act);
        if (act) {
            int pos1 = atomicAdd(&cnt1[b * TT + t], 1);
            if (pos1 < CAP1) idx1[(size_t)(b * TT + t) * CAP1 + pos1] = (unsigned short)din;
            int pos = kbase + __popcll(m & ((1ull << lane) - 1ull));
            if (pos < KMAX) times1[(size_t)row * KMAX + pos] = (unsigned short)t;
        }
        kbase += __popcll(m);
    }
    if (lane == 0) kcnt[row] = kbase;
}

// Reduce cnt1 -> sum_sp[0]
__global__ void k_sum0(const int* __restrict__ cnt1, float* __restrict__ out) {
    __shared__ int red[4];
    int s = 0;
    for (int i = threadIdx.x; i < BB * TT; i += 256) s += cnt1[i];
    for (int d = 32; d >= 1; d >>= 1) s += __shfl_down(s, d, 64);
    int w = threadIdx.x >> 6;
    if ((threadIdx.x & 63) == 0) red[w] = s;
    __syncthreads();
    if (threadIdx.x == 0)
        out[SUM_OFF + 0] = (float)(red[0] + red[1] + red[2] + red[3]);
}

// c1[b,t,:] = sum over active din of W1T[din,:]
__global__ __launch_bounds__(256) void k_c1(const int* __restrict__ cnt1,
                                            const unsigned short* __restrict__ idx1,
                                            const float* __restrict__ W1T,
                                            float* __restrict__ c1) {
    int blk = blockIdx.x;                 // b*TT + t
    int cnt = cnt1[blk];
    if (cnt > CAP1) cnt = CAP1;
    __shared__ int sidx[CAP1];
    for (int j = threadIdx.x; j < cnt; j += 256) sidx[j] = idx1[(size_t)blk * CAP1 + j];
    __syncthreads();
    int tid = threadIdx.x;
    if (tid < 200) {
        float ax = 0.f, ay = 0.f, az = 0.f, aw = 0.f;
        for (int j = 0; j < cnt; ++j) {
            const float4* row = (const float4*)(W1T + (size_t)sidx[j] * HH);
            float4 w = row[tid];
            ax += w.x; ay += w.y; az += w.z; aw += w.w;
        }
        float4 o; o.x = ax; o.y = ay; o.z = az; o.w = aw;
        ((float4*)(c1 + (size_t)blk * HH))[tid] = o;
    }
}

// Per-(b,h): scan um/us recurrence, find first crossing -> t1, h1_dtdu, spk1 lists.
__global__ void k_scan1(const float* __restrict__ c1, int* __restrict__ t1,
                        int* __restrict__ cnt2, unsigned short* __restrict__ idx2,
                        float* __restrict__ out) {
    int id = blockIdx.x * 64 + threadIdx.x;   // 25600 = 400 * 64
    int b = id / HH, h = id - b * HH;
    float um = 0.f, us = 0.f;
    bool done = false;
    int t1v = TT;
    const float* cbase = c1 + (size_t)b * TT * HH + h;
    for (int t = 0; t < TT; ++t) {
        float c = cbase[(size_t)t * HH];
        um = um * DM_F + c;
        us = us * DS_F + c;
        float u = um - us;
        if (u >= 1.0f) {
            done = true; t1v = t;
            float dudt = -um / 20.0f + us / 5.0f;
            dudt = (dudt >= 0.f) ? fmaxf(dudt, 1e-2f) : fminf(dudt, -1e-2f);
            out[H1DT_OFF + (size_t)id] = 1.f / dudt;
            int pos = atomicAdd(&cnt2[b * TT + t], 1);
            idx2[(size_t)(b * TT + t) * HH + pos] = (unsigned short)h;
            break;
        }
    }
    if (!done) out[H1DT_OFF + (size_t)id] = 0.f;
    t1[id] = t1v;
    unsigned long long m = __ballot(done);
    if (threadIdx.x == 0 && m) atomicAdd(&out[SUM_OFF + 1], (float)__popcll(m));
}

// Layer-2 scan per batch: out_t, out_u, h2_dtdu, t2, spk2 count.
__global__ void k_layer2(const int* __restrict__ cnt2, const unsigned short* __restrict__ idx2,
                         const float* __restrict__ W2, int* __restrict__ t2,
                         float* __restrict__ out) {
    int b = blockIdx.x, tid = threadIdx.x;   // 64 threads, lanes 0..9 own outputs
    float um = 0.f, us = 0.f, u2 = 0.f, dtdu = 0.f;
    bool done = false;
    int t2v = TT;
    for (int t = 0; t < TT; ++t) {
        float c = 0.f;
        int cnt = cnt2[b * TT + t];
        if (tid < OO) {
            const unsigned short* lp = idx2 + (size_t)(b * TT + t) * HH;
            for (int j = 0; j < cnt; ++j) {
                int hh = lp[j];
                c += W2[tid * HH + hh];
            }
        }
        um = um * DM_F + c;
        us = us * DS_F + c;
        if (!done) {
            float u = um - us;
            if (u >= 1.0f) {
                done = true; t2v = t; u2 = u;
                float dudt = -um / 20.0f + us / 5.0f;
                dudt = (dudt >= 0.f) ? fmaxf(dudt, 1e-2f) : fminf(dudt, -1e-2f);
                dtdu = 1.f / dudt;
            }
        }
    }
    if (tid < OO) {
        out[OUT_T_OFF + b * OO + tid] = (float)t2v;
        out[OUT_U_OFF + b * OO + tid] = done ? u2 : 0.f;
        out[H2DT_OFF + (size_t)(b * OO + tid)] = done ? dtdu : 0.f;
        t2[b * OO + tid] = t2v;
    }
    unsigned long long m = __ballot(done && tid < OO);
    if (tid == 0 && m) atomicAdd(&out[SUM_OFF + 2], (float)__popcll(m));
}

// Closed-form h2_v / h2_dvdt: vm2(t2) = dm^(t2-t1) for single hidden spike.
__global__ void k_h2(const int* __restrict__ t1, const int* __restrict__ t2,
                     const float* __restrict__ dmp, const float* __restrict__ dsp,
                     float* __restrict__ out) {
    int blk = blockIdx.x;         // b*OO + o
    int b = blk / OO;
    int t2v = t2[blk];
    bool spk = (t2v < TT);
    for (int h = threadIdx.x; h < HH; h += 256) {
        float v = 0.f, dv = 0.f;
        if (spk) {
            int t1v = t1[b * HH + h];
            if (t1v <= t2v) {
                int k = t2v - t1v;
                float a = dmp[k], s = dsp[k];
                v = a - s;
                dv = a / 20.0f - s / 5.0f;
            }
        }
        out[H2V_OFF + (size_t)blk * HH + h] = v;
        out[H2DV_OFF + (size_t)blk * HH + h] = dv;
    }
}

// Event-based h1: one block per (b,h). h1_v[b,h,d] = sum over input spikes
// ts <= t1 of dm^(t1-ts) - ds^(t1-ts); zeros if h never spiked.
__global__ __launch_bounds__(256) void k_h1ev(const int* __restrict__ t1,
                                              const int* __restrict__ kcnt,
                                              const unsigned short* __restrict__ times1,
                                              const float* __restrict__ dmp,
                                              const float* __restrict__ dsp,
                                              float* __restrict__ out) {
    int blk = blockIdx.x;          // b*HH + h
    int b = blk / HH;
    int t1v = t1[blk];
    size_t rbase = (size_t)blk * DD;
    if (t1v >= TT) {
        for (int d = threadIdx.x; d < DD; d += 256) {
            out[H1V_OFF + rbase + d] = 0.f;
            out[H1DV_OFF + rbase + d] = 0.f;
        }
        return;
    }
    __shared__ float sm[TT], ss[TT];
    for (int i = threadIdx.x; i < TT; i += 256) { sm[i] = dmp[i]; ss[i] = dsp[i]; }
    __syncthreads();
    const int* kc = kcnt + (size_t)b * DD;
    const unsigned short* tp = times1 + (size_t)b * DD * KMAX;
    for (int d = threadIdx.x; d < DD; d += 256) {
        int k = kc[d]; if (k > KMAX) k = KMAX;
        float a = 0.f, s = 0.f;
        const unsigned short* q = tp + (size_t)d * KMAX;
        for (int j = 0; j < k; ++j) {
            int ts = q[j];
            if (ts > t1v) break;            // times are ascending
            int e = t1v - ts;
            a += sm[e]; s += ss[e];
        }
        out[H1V_OFF + rbase + d] = a - s;
        out[H1DV_OFF + rbase + d] = a * 0.05f - s * 0.2f;
    }
}

extern "C" void kernel_launch(void* const* d_in, const int* in_sizes, int n_in,
                              void* d_out, int out_size, void* d_ws, size_t ws_size,
                              hipStream_t stream) {
    (void)in_sizes; (void)n_in; (void)out_size; (void)ws_size;
    const float* in = (const float*)d_in[0];
    const float* W1 = (const float*)d_in[1];
    const float* W2 = (const float*)d_in[2];
    float* out = (float*)d_out;
    char* ws = (char*)d_ws;

    float* W1T = (float*)(ws + WS_W1T);
    float* c1  = (float*)(ws + WS_C1);
    unsigned short* idx1 = (unsigned short*)(ws + WS_IDX1);
    unsigned short* idx2 = (unsigned short*)(ws + WS_IDX2);
    int* cnt1 = (int*)(ws + WS_CNT1);
    int* cnt2 = (int*)(ws + WS_CNT2);
    int* t1   = (int*)(ws + WS_T1);
    int* t2   = (int*)(ws + WS_T2);
    float* dmp = (float*)(ws + WS_DMP);
    float* dsp = (float*)(ws + WS_DSP);
    unsigned short* times1 = (unsigned short*)(ws + WS_TIMES1);
    int* kcnt = (int*)(ws + WS_KCNT);

    // zero counters (cnt1 & cnt2 adjacent) and sum_sp outputs
    hipMemsetAsync(cnt1, 0, (size_t)BB * TT * 4 * 2, stream);
    hipMemsetAsync(out + SUM_OFF, 0, 3 * sizeof(float), stream);

    k_pow<<<1, 64, 0, stream>>>(dmp, dsp);
    k_transpose<<<dim3(73, 25), dim3(32, 32), 0, stream>>>(W1, W1T);
    k_events<<<(BB * DD) / 4, 256, 0, stream>>>(in, cnt1, idx1, times1, kcnt);
    k_sum0<<<1, 256, 0, stream>>>(cnt1, out);
    k_c1<<<BB * TT, 256, 0, stream>>>(cnt1, idx1, W1T, c1);
    k_scan1<<<(BB * HH) / 64, 64, 0, stream>>>(c1, t1, cnt2, idx2, out);
    k_layer2<<<BB, 64, 0, stream>>>(cnt2, idx2, W2, t2, out);
    k_h2<<<BB * OO, 256, 0, stream>>>(t1, t2, dmp, dsp, out);
    k_h1ev<<<BB * HH, 256, 0, stream>>>(t1, kcnt, times1, dmp, dsp, out);
}

// Round 6
// 528.234 us; speedup vs baseline: 2.9584x; 1.2539x over previous
//
#include <hip/hip_runtime.h>
#include <cstdint>
#include <cstddef>

#define BB 32
#define TT 300
#define DD 2312
#define HH 800
#define OO 10
#define CAP1 128
#define KMAX 32

typedef float f32x4 __attribute__((ext_vector_type(4)));

// exp(-1/20), exp(-1/5) correctly rounded to fp32
#define DM_F 0.95122942450071400909f
#define DS_F 0.81873075307798185867f

// d_out float offsets (concatenated tuple, return order)
#define OUT_T_OFF 0
#define OUT_U_OFF 320
#define SUM_OFF   640
#define H1V_OFF   643ull
#define H2V_OFF   59187843ull
#define H1DV_OFF  59443843ull
#define H2DV_OFF  118631043ull
#define H1DT_OFF  118887043ull
#define H2DT_OFF  118912643ull

// ws byte offsets (all 256-aligned)
#define WS_W1T    0ull
#define WS_C1     7398400ull
#define WS_IDX1   38118400ull        // u16[BB*TT*CAP1]
#define WS_CNT1   55936000ull        // int[BB*TT]
#define WS_T1     56012800ull        // int[BB*HH]
#define WS_T2     56115200ull        // int[BB*OO]
#define WS_DMP    56116480ull        // float[TT+1]
#define WS_DSP    56117760ull        // float[TT+1]
#define WS_TIMES1 56119040ull        // u16[BB*KMAX*DD] transposed (4,734,976 B)

__global__ void k_pow(float* __restrict__ dmp, float* __restrict__ dsp) {
    if (threadIdx.x == 0) {
        float v = 1.f;
        for (int i = 0; i <= TT; ++i) { dmp[i] = v; v *= DM_F; }
    }
    if (threadIdx.x == 1) {
        float v = 1.f;
        for (int i = 0; i <= TT; ++i) { dsp[i] = v; v *= DS_F; }
    }
}

__global__ void k_transpose(const float* __restrict__ W1, float* __restrict__ W1T) {
    __shared__ float tile[32][33];
    int dx = blockIdx.x * 32, hy = blockIdx.y * 32;
    int tx = threadIdx.x, ty = threadIdx.y;
    int d = dx + tx, h = hy + ty;            // h always < 800 (25*32)
    if (d < DD) tile[ty][tx] = W1[(size_t)h * DD + d];
    __syncthreads();
    int d2 = dx + ty, h2 = hy + tx;
    if (d2 < DD) W1T[(size_t)d2 * HH + h2] = tile[tx][ty];
}

// One wave per (b,din) row. Builds:
//  - per-(b,t) active-input lists (cnt1/idx1) for k_c1
//  - per-(b,d) ordered spike times, TRANSPOSED: times1T[(b*KMAX+j)*DD + d]
//    (unused slots stay 0xFFFF sentinel from the pre-fill memset)
__global__ void k_events(const float* __restrict__ in, int* __restrict__ cnt1,
                         unsigned short* __restrict__ idx1,
                         unsigned short* __restrict__ times1T) {
    int row = blockIdx.x * 4 + (threadIdx.x >> 6);   // rows = BB*DD = 73984 (divisible by 4)
    int lane = threadIdx.x & 63;
    int b = row / DD, din = row - b * DD;
    const float* p = in + (size_t)row * TT;
    int kbase = 0;
    for (int r = 0; r < 5; ++r) {
        int t = r * 64 + lane;
        float v = (t < TT) ? p[t] : 0.f;
        bool act = (v != 0.f);
        unsigned long long m = __ballot(act);
        if (act) {
            int pos1 = atomicAdd(&cnt1[b * TT + t], 1);
            if (pos1 < CAP1) idx1[(size_t)(b * TT + t) * CAP1 + pos1] = (unsigned short)din;
            int pos = kbase + __popcll(m & ((1ull << lane) - 1ull));
            if (pos < KMAX)
                times1T[((size_t)b * KMAX + pos) * DD + din] = (unsigned short)t;
        }
        kbase += __popcll(m);
    }
}

// c1[b,t,:] = sum over active din of W1T[din,:]
__global__ __launch_bounds__(256) void k_c1(const int* __restrict__ cnt1,
                                            const unsigned short* __restrict__ idx1,
                                            const float* __restrict__ W1T,
                                            float* __restrict__ c1) {
    int blk = blockIdx.x;                 // b*TT + t
    int cnt = cnt1[blk];
    if (cnt > CAP1) cnt = CAP1;
    __shared__ int sidx[CAP1];
    for (int j = threadIdx.x; j < cnt; j += 256) sidx[j] = idx1[(size_t)blk * CAP1 + j];
    __syncthreads();
    int tid = threadIdx.x;
    if (tid < 200) {
        f32x4 acc = {0.f, 0.f, 0.f, 0.f};
        for (int j = 0; j < cnt; ++j) {
            const f32x4* row = (const f32x4*)(W1T + (size_t)sidx[j] * HH);
            acc += row[tid];
        }
        ((f32x4*)(c1 + (size_t)blk * HH))[tid] = acc;
    }
}

// Per-(b,h): scan um/us recurrence, first crossing -> t1, h1_dtdu. No atomics.
__global__ void k_scan1(const float* __restrict__ c1, int* __restrict__ t1,
                        float* __restrict__ out) {
    int id = blockIdx.x * 64 + threadIdx.x;   // 25600 = 400 * 64
    int b = id / HH, h = id - b * HH;
    float um = 0.f, us = 0.f;
    bool done = false;
    int t1v = TT;
    const float* cbase = c1 + (size_t)b * TT * HH + h;
    for (int t = 0; t < TT; ++t) {
        float c = cbase[(size_t)t * HH];
        um = um * DM_F + c;
        us = us * DS_F + c;
        float u = um - us;
        if (u >= 1.0f) {
            done = true; t1v = t;
            float dudt = -um / 20.0f + us / 5.0f;
            dudt = (dudt >= 0.f) ? fmaxf(dudt, 1e-2f) : fminf(dudt, -1e-2f);
            out[H1DT_OFF + (size_t)id] = 1.f / dudt;
            break;
        }
    }
    if (!done) out[H1DT_OFF + (size_t)id] = 0.f;
    t1[id] = t1v;
}

// Layer-2, one block per b: build c2[o][t] in LDS from t1 (parallel over h),
// then 10 lanes scan. Block 0 additionally reduces sum_sp[0] and sum_sp[1].
__global__ __launch_bounds__(256) void k_layer2(const int* __restrict__ t1,
                                                const int* __restrict__ cnt1,
                                                const float* __restrict__ W2,
                                                int* __restrict__ t2,
                                                float* __restrict__ out) {
    __shared__ float c2[OO][TT];
    __shared__ int red[4];
    int b = blockIdx.x, tid = threadIdx.x;
    for (int i = tid; i < OO * TT; i += 256) ((float*)c2)[i] = 0.f;
    __syncthreads();
    for (int h = tid; h < HH; h += 256) {
        int t = t1[b * HH + h];
        if (t < TT) {
            #pragma unroll
            for (int o = 0; o < OO; ++o) atomicAdd(&c2[o][t], W2[o * HH + h]);
        }
    }
    __syncthreads();
    bool done = false;
    if (tid < OO) {
        float um = 0.f, us = 0.f, u2 = 0.f, dtdu = 0.f;
        int t2v = TT;
        for (int t = 0; t < TT; ++t) {
            float c = c2[tid][t];
            um = um * DM_F + c;
            us = us * DS_F + c;
            float u = um - us;
            if (u >= 1.0f) {
                done = true; t2v = t; u2 = u;
                float dudt = -um / 20.0f + us / 5.0f;
                dudt = (dudt >= 0.f) ? fmaxf(dudt, 1e-2f) : fminf(dudt, -1e-2f);
                dtdu = 1.f / dudt;
                break;
            }
        }
        out[OUT_T_OFF + b * OO + tid] = (float)t2v;
        out[OUT_U_OFF + b * OO + tid] = done ? u2 : 0.f;
        out[H2DT_OFF + (size_t)(b * OO + tid)] = done ? dtdu : 0.f;
        t2[b * OO + tid] = t2v;
    }
    unsigned long long m = __ballot(done);
    if (tid == 0 && m) atomicAdd(&out[SUM_OFF + 2], (float)__popcll(m));

    if (blockIdx.x == 0) {
        // sum_sp[0] = total input spikes (from cnt1); sum_sp[1] = #(t1 < TT)
        int s0 = 0, s1 = 0;
        for (int i = tid; i < BB * TT; i += 256) s0 += cnt1[i];
        for (int i = tid; i < BB * HH; i += 256) s1 += (t1[i] < TT);
        for (int d = 32; d >= 1; d >>= 1) {
            s0 += __shfl_down(s0, d, 64);
            s1 += __shfl_down(s1, d, 64);
        }
        int w = tid >> 6;
        if ((tid & 63) == 0) red[w] = s0;
        __syncthreads();
        if (tid == 0) out[SUM_OFF + 0] = (float)(red[0] + red[1] + red[2] + red[3]);
        __syncthreads();
        if ((tid & 63) == 0) red[w] = s1;
        __syncthreads();
        if (tid == 0) out[SUM_OFF + 1] = (float)(red[0] + red[1] + red[2] + red[3]);
    }
}

// Closed-form h2_v / h2_dvdt: vm2(t2) = dm^(t2-t1) for single hidden spike.
__global__ void k_h2(const int* __restrict__ t1, const int* __restrict__ t2,
                     const float* __restrict__ dmp, const float* __restrict__ dsp,
                     float* __restrict__ out) {
    int blk = blockIdx.x;         // b*OO + o
    int b = blk / OO;
    int t2v = t2[blk];
    bool spk = (t2v < TT);
    for (int h = threadIdx.x; h < HH; h += 256) {
        float v = 0.f, dv = 0.f;
        if (spk) {
            int t1v = t1[b * HH + h];
            if (t1v <= t2v) {
                int k = t2v - t1v;
                float a = dmp[k], s = dsp[k];
                v = a - s;
                dv = a / 20.0f - s / 5.0f;
            }
        }
        out[H2V_OFF + (size_t)blk * HH + h] = v;
        out[H2DV_OFF + (size_t)blk * HH + h] = dv;
    }
}

// Event-based h1, one block per (b,h). Coalesced transposed time-list reads,
// aligned f32x4 nontemporal stores (out offsets are ==3 mod 4: 1 lead scalar,
// 577 float4 groups covering d=1..2308, 3 tail scalars).
struct AS { float a, s; };

__device__ __forceinline__ AS h1_accum(const unsigned short* __restrict__ tp,
                                       int d, int t1v,
                                       const float* __restrict__ sm,
                                       const float* __restrict__ ss) {
    AS r; r.a = 0.f; r.s = 0.f;
    #pragma unroll 1
    for (int j = 0; j < KMAX; ++j) {
        int ts = tp[(size_t)j * DD + d];
        if (ts > t1v) break;                 // ascending; sentinel 0xFFFF ends list
        int e = t1v - ts;
        r.a += sm[e]; r.s += ss[e];
    }
    return r;
}

__global__ __launch_bounds__(256) void k_h1ev(const int* __restrict__ t1,
                                              const unsigned short* __restrict__ times1T,
                                              const float* __restrict__ dmp,
                                              const float* __restrict__ dsp,
                                              float* __restrict__ out) {
    int blk = blockIdx.x;          // b*HH + h
    int b = blk / HH;
    int t1v = t1[blk];
    size_t rbase = (size_t)blk * DD;
    float* pv = out + H1V_OFF + rbase;
    float* pd = out + H1DV_OFF + rbase;
    int tid = threadIdx.x;
    if (t1v >= TT) {
        f32x4 z = {0.f, 0.f, 0.f, 0.f};
        for (int g = tid; g < 577; g += 256) {
            __builtin_nontemporal_store(z, (f32x4*)(pv + 1 + g * 4));
            __builtin_nontemporal_store(z, (f32x4*)(pd + 1 + g * 4));
        }
        if (tid < 4) {
            int d = (tid == 0) ? 0 : 2308 + tid;
            __builtin_nontemporal_store(0.f, pv + d);
            __builtin_nontemporal_store(0.f, pd + d);
        }
        return;
    }
    __shared__ float sm[TT], ss[TT];
    for (int i = tid; i < TT; i += 256) { sm[i] = dmp[i]; ss[i] = dsp[i]; }
    __syncthreads();
    const unsigned short* tp = times1T + (size_t)b * KMAX * DD;
    for (int g = tid; g < 577; g += 256) {
        int d0 = 1 + g * 4;
        AS r0 = h1_accum(tp, d0 + 0, t1v, sm, ss);
        AS r1 = h1_accum(tp, d0 + 1, t1v, sm, ss);
        AS r2 = h1_accum(tp, d0 + 2, t1v, sm, ss);
        AS r3 = h1_accum(tp, d0 + 3, t1v, sm, ss);
        f32x4 v4 = {r0.a - r0.s, r1.a - r1.s, r2.a - r2.s, r3.a - r3.s};
        f32x4 d4 = {r0.a * 0.05f - r0.s * 0.2f, r1.a * 0.05f - r1.s * 0.2f,
                    r2.a * 0.05f - r2.s * 0.2f, r3.a * 0.05f - r3.s * 0.2f};
        __builtin_nontemporal_store(v4, (f32x4*)(pv + d0));
        __builtin_nontemporal_store(d4, (f32x4*)(pd + d0));
    }
    if (tid < 4) {
        int d = (tid == 0) ? 0 : 2308 + tid;
        AS r = h1_accum(tp, d, t1v, sm, ss);
        __builtin_nontemporal_store(r.a - r.s, pv + d);
        __builtin_nontemporal_store(r.a * 0.05f - r.s * 0.2f, pd + d);
    }
}

extern "C" void kernel_launch(void* const* d_in, const int* in_sizes, int n_in,
                              void* d_out, int out_size, void* d_ws, size_t ws_size,
                              hipStream_t stream) {
    (void)in_sizes; (void)n_in; (void)out_size; (void)ws_size;
    const float* in = (const float*)d_in[0];
    const float* W1 = (const float*)d_in[1];
    const float* W2 = (const float*)d_in[2];
    float* out = (float*)d_out;
    char* ws = (char*)d_ws;

    float* W1T = (float*)(ws + WS_W1T);
    float* c1  = (float*)(ws + WS_C1);
    unsigned short* idx1 = (unsigned short*)(ws + WS_IDX1);
    int* cnt1 = (int*)(ws + WS_CNT1);
    int* t1   = (int*)(ws + WS_T1);
    int* t2   = (int*)(ws + WS_T2);
    float* dmp = (float*)(ws + WS_DMP);
    float* dsp = (float*)(ws + WS_DSP);
    unsigned short* times1T = (unsigned short*)(ws + WS_TIMES1);

    (void)hipMemsetAsync(cnt1, 0, (size_t)BB * TT * 4, stream);
    (void)hipMemsetAsync(times1T, 0xFF, (size_t)BB * KMAX * DD * 2, stream);
    (void)hipMemsetAsync(out + SUM_OFF, 0, 3 * sizeof(float), stream);

    k_pow<<<1, 64, 0, stream>>>(dmp, dsp);
    k_transpose<<<dim3(73, 25), dim3(32, 32), 0, stream>>>(W1, W1T);
    k_events<<<(BB * DD) / 4, 256, 0, stream>>>(in, cnt1, idx1, times1T);
    k_c1<<<BB * TT, 256, 0, stream>>>(cnt1, idx1, W1T, c1);
    k_scan1<<<(BB * HH) / 64, 64, 0, stream>>>(c1, t1, out);
    k_layer2<<<BB, 256, 0, stream>>>(t1, cnt1, W2, t2, out);
    k_h2<<<BB * OO, 256, 0, stream>>>(t1, t2, dmp, dsp, out);
    k_h1ev<<<BB * HH, 256, 0, stream>>>(t1, times1T, dmp, dsp, out);
}

// Round 7
// 434.400 us; speedup vs baseline: 3.5974x; 1.2160x over previous
//
#include <hip/hip_runtime.h>
#include <cstdint>
#include <cstddef>

#define BB 32
#define TT 300
#define DD 2312
#define HH 800
#define OO 10
#define CAP1 128
#define KMAX 32

typedef float f32x4 __attribute__((ext_vector_type(4)));

// exp(-1/20), exp(-1/5) correctly rounded to fp32
#define DM_F 0.95122942450071400909f
#define DS_F 0.81873075307798185867f

// d_out float offsets (concatenated tuple, return order)
#define OUT_T_OFF 0
#define OUT_U_OFF 320
#define SUM_OFF   640
#define H1V_OFF   643ull
#define H2V_OFF   59187843ull
#define H1DV_OFF  59443843ull
#define H2DV_OFF  118631043ull
#define H1DT_OFF  118887043ull
#define H2DT_OFF  118912643ull

// ws byte offsets (all 256-aligned)
#define WS_W1T    0ull
#define WS_C1     7398400ull
#define WS_IDX1   38118400ull        // u16[BB*TT*CAP1]
#define WS_CNT1   55936000ull        // int[BB*TT]
#define WS_T1     56012800ull        // int[BB*HH]
#define WS_T2     56115200ull        // int[BB*OO]
#define WS_DMP    56116480ull        // float[TT+1]
#define WS_DSP    56117760ull        // float[TT+1]
#define WS_TIMES1 56119040ull        // u16[BB*KMAX*DD] transposed (4,734,976 B)

__global__ void k_pow(float* __restrict__ dmp, float* __restrict__ dsp) {
    if (threadIdx.x == 0) {
        float v = 1.f;
        for (int i = 0; i <= TT; ++i) { dmp[i] = v; v *= DM_F; }
    }
    if (threadIdx.x == 1) {
        float v = 1.f;
        for (int i = 0; i <= TT; ++i) { dsp[i] = v; v *= DS_F; }
    }
}

__global__ void k_transpose(const float* __restrict__ W1, float* __restrict__ W1T) {
    __shared__ float tile[32][33];
    int dx = blockIdx.x * 32, hy = blockIdx.y * 32;
    int tx = threadIdx.x, ty = threadIdx.y;
    int d = dx + tx, h = hy + ty;            // h always < 800 (25*32)
    if (d < DD) tile[ty][tx] = W1[(size_t)h * DD + d];
    __syncthreads();
    int d2 = dx + ty, h2 = hy + tx;
    if (d2 < DD) W1T[(size_t)d2 * HH + h2] = tile[tx][ty];
}

// One wave per (b,din) row. Builds:
//  - per-(b,t) active-input lists (cnt1/idx1) for k_c1
//  - per-(b,d) ordered spike times, TRANSPOSED: times1T[(b*KMAX+j)*DD + d],
//    with a single 0xFFFF sentinel written at position kbase (no memset needed)
__global__ void k_events(const float* __restrict__ in, int* __restrict__ cnt1,
                         unsigned short* __restrict__ idx1,
                         unsigned short* __restrict__ times1T) {
    int row = blockIdx.x * 4 + (threadIdx.x >> 6);   // rows = BB*DD = 73984 (divisible by 4)
    int lane = threadIdx.x & 63;
    int b = row / DD, din = row - b * DD;
    const float* p = in + (size_t)row * TT;
    int kbase = 0;
    for (int r = 0; r < 5; ++r) {
        int t = r * 64 + lane;
        float v = (t < TT) ? p[t] : 0.f;
        bool act = (v != 0.f);
        unsigned long long m = __ballot(act);
        if (act) {
            int pos1 = atomicAdd(&cnt1[b * TT + t], 1);
            if (pos1 < CAP1) idx1[(size_t)(b * TT + t) * CAP1 + pos1] = (unsigned short)din;
            int pos = kbase + __popcll(m & ((1ull << lane) - 1ull));
            if (pos < KMAX)
                times1T[((size_t)b * KMAX + pos) * DD + din] = (unsigned short)t;
        }
        kbase += __popcll(m);
    }
    if (lane == 0 && kbase < KMAX)
        times1T[((size_t)b * KMAX + kbase) * DD + din] = 0xFFFFu;
}

// c1[b,t,chunk*400 : chunk*400+400] = sum over active din of W1T[din, chunk-half].
// Chunk-major grid: blocks [0,9600) touch only W1T columns 0:400 (3.7 MB,
// L2-resident per XCD), blocks [9600,19200) only columns 400:800.
__global__ __launch_bounds__(128) void k_c1(const int* __restrict__ cnt1,
                                            const unsigned short* __restrict__ idx1,
                                            const float* __restrict__ W1T,
                                            float* __restrict__ c1) {
    int blk = blockIdx.x % (BB * TT);     // b*TT + t
    int chunk = blockIdx.x / (BB * TT);   // 0 or 1
    int cnt = cnt1[blk];
    if (cnt > CAP1) cnt = CAP1;
    __shared__ int sidx[CAP1];
    for (int j = threadIdx.x; j < cnt; j += 128) sidx[j] = idx1[(size_t)blk * CAP1 + j];
    __syncthreads();
    int tid = threadIdx.x;
    if (tid < 100) {
        int v4i = chunk * 100 + tid;
        f32x4 acc = {0.f, 0.f, 0.f, 0.f};
        for (int j = 0; j < cnt; ++j) {
            const f32x4* row = (const f32x4*)(W1T + (size_t)sidx[j] * HH);
            acc += row[v4i];
        }
        ((f32x4*)(c1 + (size_t)blk * HH))[v4i] = acc;
    }
}

// Per-(b,h): branchless 300-step scan (latching selects, unconditional loads
// pipeline), first crossing -> t1, h1_dtdu.
__global__ void k_scan1(const float* __restrict__ c1, int* __restrict__ t1,
                        float* __restrict__ out) {
    int id = blockIdx.x * 64 + threadIdx.x;   // 25600 = 400 * 64
    int b = id / HH, h = id - b * HH;
    float um = 0.f, us = 0.f, umx = 0.f, usx = 0.f;
    int t1v = TT;
    const float* cbase = c1 + (size_t)b * TT * HH + h;
    #pragma unroll 4
    for (int t = 0; t < TT; ++t) {
        float c = cbase[(size_t)t * HH];
        um = um * DM_F + c;
        us = us * DS_F + c;
        bool cross = (um - us >= 1.0f) && (t1v == TT);
        t1v = cross ? t : t1v;
        umx = cross ? um : umx;
        usx = cross ? us : usx;
    }
    float dt = 0.f;
    if (t1v < TT) {
        float dudt = -umx / 20.0f + usx / 5.0f;
        dudt = (dudt >= 0.f) ? fmaxf(dudt, 1e-2f) : fminf(dudt, -1e-2f);
        dt = 1.f / dudt;
    }
    out[H1DT_OFF + (size_t)id] = dt;
    t1[id] = t1v;
}

// Layer-2, one block per b: build c2[o][t] in LDS from t1 (parallel over h),
// then 10 lanes scan. Block 0 additionally reduces sum_sp[0] and sum_sp[1].
__global__ __launch_bounds__(256) void k_layer2(const int* __restrict__ t1,
                                                const int* __restrict__ cnt1,
                                                const float* __restrict__ W2,
                                                int* __restrict__ t2,
                                                float* __restrict__ out) {
    __shared__ float c2[OO][TT];
    __shared__ int red[4];
    int b = blockIdx.x, tid = threadIdx.x;
    for (int i = tid; i < OO * TT; i += 256) ((float*)c2)[i] = 0.f;
    __syncthreads();
    for (int h = tid; h < HH; h += 256) {
        int t = t1[b * HH + h];
        if (t < TT) {
            #pragma unroll
            for (int o = 0; o < OO; ++o) atomicAdd(&c2[o][t], W2[o * HH + h]);
        }
    }
    __syncthreads();
    bool done = false;
    if (tid < OO) {
        float um = 0.f, us = 0.f, u2 = 0.f, dtdu = 0.f;
        int t2v = TT;
        for (int t = 0; t < TT; ++t) {
            float c = c2[tid][t];
            um = um * DM_F + c;
            us = us * DS_F + c;
            float u = um - us;
            if (u >= 1.0f) {
                done = true; t2v = t; u2 = u;
                float dudt = -um / 20.0f + us / 5.0f;
                dudt = (dudt >= 0.f) ? fmaxf(dudt, 1e-2f) : fminf(dudt, -1e-2f);
                dtdu = 1.f / dudt;
                break;
            }
        }
        out[OUT_T_OFF + b * OO + tid] = (float)t2v;
        out[OUT_U_OFF + b * OO + tid] = done ? u2 : 0.f;
        out[H2DT_OFF + (size_t)(b * OO + tid)] = done ? dtdu : 0.f;
        t2[b * OO + tid] = t2v;
    }
    unsigned long long m = __ballot(done);
    if (tid == 0 && m) atomicAdd(&out[SUM_OFF + 2], (float)__popcll(m));

    if (blockIdx.x == 0) {
        // sum_sp[0] = total input spikes (from cnt1); sum_sp[1] = #(t1 < TT)
        int s0 = 0, s1 = 0;
        for (int i = tid; i < BB * TT; i += 256) s0 += cnt1[i];
        for (int i = tid; i < BB * HH; i += 256) s1 += (t1[i] < TT);
        for (int d = 32; d >= 1; d >>= 1) {
            s0 += __shfl_down(s0, d, 64);
            s1 += __shfl_down(s1, d, 64);
        }
        int w = tid >> 6;
        if ((tid & 63) == 0) red[w] = s0;
        __syncthreads();
        if (tid == 0) out[SUM_OFF + 0] = (float)(red[0] + red[1] + red[2] + red[3]);
        __syncthreads();
        if ((tid & 63) == 0) red[w] = s1;
        __syncthreads();
        if (tid == 0) out[SUM_OFF + 1] = (float)(red[0] + red[1] + red[2] + red[3]);
    }
}

// Closed-form h2_v / h2_dvdt: vm2(t2) = dm^(t2-t1) for single hidden spike.
__global__ void k_h2(const int* __restrict__ t1, const int* __restrict__ t2,
                     const float* __restrict__ dmp, const float* __restrict__ dsp,
                     float* __restrict__ out) {
    int blk = blockIdx.x;         // b*OO + o
    int b = blk / OO;
    int t2v = t2[blk];
    bool spk = (t2v < TT);
    for (int h = threadIdx.x; h < HH; h += 256) {
        float v = 0.f, dv = 0.f;
        if (spk) {
            int t1v = t1[b * HH + h];
            if (t1v <= t2v) {
                int k = t2v - t1v;
                float a = dmp[k], s = dsp[k];
                v = a - s;
                dv = a / 20.0f - s / 5.0f;
            }
        }
        out[H2V_OFF + (size_t)blk * HH + h] = v;
        out[H2DV_OFF + (size_t)blk * HH + h] = dv;
    }
}

// Event-based h1, one block per (b,h). Coalesced transposed time-list reads,
// aligned f32x4 nontemporal stores (out offsets are ==3 mod 4: 1 lead scalar,
// 577 float4 groups covering d=1..2308, 3 tail scalars).
struct AS { float a, s; };

__device__ __forceinline__ AS h1_accum(const unsigned short* __restrict__ tp,
                                       int d, int t1v,
                                       const float* __restrict__ sm,
                                       const float* __restrict__ ss) {
    AS r; r.a = 0.f; r.s = 0.f;
    #pragma unroll 1
    for (int j = 0; j < KMAX; ++j) {
        int ts = tp[(size_t)j * DD + d];
        if (ts > t1v) break;                 // ascending; sentinel 0xFFFF ends list
        int e = t1v - ts;
        r.a += sm[e]; r.s += ss[e];
    }
    return r;
}

__global__ __launch_bounds__(256) void k_h1ev(const int* __restrict__ t1,
                                              const unsigned short* __restrict__ times1T,
                                              const float* __restrict__ dmp,
                                              const float* __restrict__ dsp,
                                              float* __restrict__ out) {
    int blk = blockIdx.x;          // b*HH + h
    int b = blk / HH;
    int t1v = t1[blk];
    size_t rbase = (size_t)blk * DD;
    float* pv = out + H1V_OFF + rbase;
    float* pd = out + H1DV_OFF + rbase;
    int tid = threadIdx.x;
    if (t1v >= TT) {
        f32x4 z = {0.f, 0.f, 0.f, 0.f};
        for (int g = tid; g < 577; g += 256) {
            __builtin_nontemporal_store(z, (f32x4*)(pv + 1 + g * 4));
            __builtin_nontemporal_store(z, (f32x4*)(pd + 1 + g * 4));
        }
        if (tid < 4) {
            int d = (tid == 0) ? 0 : 2308 + tid;
            __builtin_nontemporal_store(0.f, pv + d);
            __builtin_nontemporal_store(0.f, pd + d);
        }
        return;
    }
    __shared__ float sm[TT], ss[TT];
    for (int i = tid; i < TT; i += 256) { sm[i] = dmp[i]; ss[i] = dsp[i]; }
    __syncthreads();
    const unsigned short* tp = times1T + (size_t)b * KMAX * DD;
    for (int g = tid; g < 577; g += 256) {
        int d0 = 1 + g * 4;
        AS r0 = h1_accum(tp, d0 + 0, t1v, sm, ss);
        AS r1 = h1_accum(tp, d0 + 1, t1v, sm, ss);
        AS r2 = h1_accum(tp, d0 + 2, t1v, sm, ss);
        AS r3 = h1_accum(tp, d0 + 3, t1v, sm, ss);
        f32x4 v4 = {r0.a - r0.s, r1.a - r1.s, r2.a - r2.s, r3.a - r3.s};
        f32x4 d4 = {r0.a * 0.05f - r0.s * 0.2f, r1.a * 0.05f - r1.s * 0.2f,
                    r2.a * 0.05f - r2.s * 0.2f, r3.a * 0.05f - r3.s * 0.2f};
        __builtin_nontemporal_store(v4, (f32x4*)(pv + d0));
        __builtin_nontemporal_store(d4, (f32x4*)(pd + d0));
    }
    if (tid < 4) {
        int d = (tid == 0) ? 0 : 2308 + tid;
        AS r = h1_accum(tp, d, t1v, sm, ss);
        __builtin_nontemporal_store(r.a - r.s, pv + d);
        __builtin_nontemporal_store(r.a * 0.05f - r.s * 0.2f, pd + d);
    }
}

extern "C" void kernel_launch(void* const* d_in, const int* in_sizes, int n_in,
                              void* d_out, int out_size, void* d_ws, size_t ws_size,
                              hipStream_t stream) {
    (void)in_sizes; (void)n_in; (void)out_size; (void)ws_size;
    const float* in = (const float*)d_in[0];
    const float* W1 = (const float*)d_in[1];
    const float* W2 = (const float*)d_in[2];
    float* out = (float*)d_out;
    char* ws = (char*)d_ws;

    float* W1T = (float*)(ws + WS_W1T);
    float* c1  = (float*)(ws + WS_C1);
    unsigned short* idx1 = (unsigned short*)(ws + WS_IDX1);
    int* cnt1 = (int*)(ws + WS_CNT1);
    int* t1   = (int*)(ws + WS_T1);
    int* t2   = (int*)(ws + WS_T2);
    float* dmp = (float*)(ws + WS_DMP);
    float* dsp = (float*)(ws + WS_DSP);
    unsigned short* times1T = (unsigned short*)(ws + WS_TIMES1);

    (void)hipMemsetAsync(cnt1, 0, (size_t)BB * TT * 4, stream);
    (void)hipMemsetAsync(out + SUM_OFF, 0, 3 * sizeof(float), stream);

    k_pow<<<1, 64, 0, stream>>>(dmp, dsp);
    k_transpose<<<dim3(73, 25), dim3(32, 32), 0, stream>>>(W1, W1T);
    k_events<<<(BB * DD) / 4, 256, 0, stream>>>(in, cnt1, idx1, times1T);
    k_c1<<<2 * BB * TT, 128, 0, stream>>>(cnt1, idx1, W1T, c1);
    k_scan1<<<(BB * HH) / 64, 64, 0, stream>>>(c1, t1, out);
    k_layer2<<<BB, 256, 0, stream>>>(t1, cnt1, W2, t2, out);
    k_h2<<<BB * OO, 256, 0, stream>>>(t1, t2, dmp, dsp, out);
    k_h1ev<<<BB * HH, 256, 0, stream>>>(t1, times1T, dmp, dsp, out);
}